// Round 4
// baseline (4616.797 us; speedup 1.0000x reference)
//
#include <hip/hip_runtime.h>

#define NN 100000   // nodes
#define NE 1600000  // edges
#define NR 8        // relations
#define DD 128      // feature dim
#define NKEY (NN * NR)               // 800000 (dst,rel) keys
#define NBLK ((NKEY + 1023) / 1024)  // 782 scan blocks
#define ROWS 1028                    // agg row stride (f32) -> 2-way (free) A-frag reads
#define MAPC 2112                    // position->key map capacity per block

typedef __attribute__((ext_vector_type(8))) short short8;
typedef __attribute__((ext_vector_type(4))) float f32x4;

__device__ __forceinline__ float bf2f(unsigned short u) {
  union { unsigned int i; float f; } c; c.i = ((unsigned int)u) << 16; return c.f;
}
__device__ __forceinline__ unsigned short f2bf(float f) {
  union { float f; unsigned int i; } c; c.f = f;
  unsigned int u = c.i;
  return (unsigned short)((u + 0x7FFFu + ((u >> 16) & 1u)) >> 16);  // RNE
}

// ---- preprocessing ----------------------------------------------------------

__global__ __launch_bounds__(256) void k_cast(
    const float* __restrict__ x, unsigned short* __restrict__ xb) {
  int i = blockIdx.x * 256 + threadIdx.x;          // over N*D/4
  if (i < NN * DD / 4) {
    float4 f = ((const float4*)x)[i];
    ushort4 u;
    u.x = f2bf(f.x); u.y = f2bf(f.y); u.z = f2bf(f.z); u.w = f2bf(f.w);
    ((ushort4*)xb)[i] = u;
  }
}

// wbf[layer][rb][n][k] = W[rb][k][n]  (rb==8 -> root), bf16
__global__ __launch_bounds__(256) void k_wtrans(
    const float* __restrict__ W1, const float* __restrict__ root1,
    const float* __restrict__ W2, const float* __restrict__ root2,
    unsigned short* __restrict__ wbf) {
  int idx = blockIdx.x * 256 + threadIdx.x;        // 2*9*16384 total
  int layer = idx / (9 * 16384);
  int rem = idx % (9 * 16384);
  int r = rem / 16384;
  int nk = rem % 16384;
  int n = nk >> 7, k = nk & 127;
  float v;
  if (r < 8) v = (layer ? W2 : W1)[r * 16384 + k * 128 + n];
  else       v = (layer ? root2 : root1)[k * 128 + n];
  wbf[idx] = f2bf(v);
}

__global__ __launch_bounds__(256) void k_zero(int* __restrict__ p, int n) {
  int i = blockIdx.x * 256 + threadIdx.x;
  if (i < n) p[i] = 0;
}

__global__ __launch_bounds__(256) void k_count(
    const int* __restrict__ ei, const int* __restrict__ et, int* __restrict__ cnt) {
  int e = blockIdx.x * 256 + threadIdx.x;
  if (e < NE) {
    int dst = ei[NE + e];
    int r = et[e];
    atomicAdd(&cnt[dst * NR + r], 1);
  }
}

// hierarchical exclusive scan over NKEY elements
__global__ __launch_bounds__(1024) void k_scan1(
    const int* __restrict__ cnt, int* __restrict__ offs, int* __restrict__ bsum) {
  __shared__ int sd[1024];
  int t = threadIdx.x, b = blockIdx.x;
  int i = b * 1024 + t;
  int v = (i < NKEY) ? cnt[i] : 0;
  sd[t] = v;
  __syncthreads();
  for (int o = 1; o < 1024; o <<= 1) {
    int tv = (t >= o) ? sd[t - o] : 0;
    __syncthreads();
    sd[t] += tv;
    __syncthreads();
  }
  if (i < NKEY) offs[i] = sd[t] - v;               // block-local exclusive
  if (t == 1023) bsum[b] = sd[t];
}

__global__ __launch_bounds__(1024) void k_scan2(int* __restrict__ bsum) {
  __shared__ int sd[1024];
  int t = threadIdx.x;
  int v = (t < NBLK) ? bsum[t] : 0;
  sd[t] = v;
  __syncthreads();
  for (int o = 1; o < 1024; o <<= 1) {
    int tv = (t >= o) ? sd[t - o] : 0;
    __syncthreads();
    sd[t] += tv;
    __syncthreads();
  }
  if (t < NBLK) bsum[t] = sd[t] - v;               // exclusive block bases
}

__global__ __launch_bounds__(256) void k_scan3(
    int* __restrict__ offs, const int* __restrict__ bsum) {
  int i = blockIdx.x * 256 + threadIdx.x;
  if (i < NKEY) offs[i] += bsum[i >> 10];
  if (i == 0) offs[NKEY] = NE;                     // total is always NE
}

// scatter edges; reuses cnt as the fill counter (atomicSub), so no `fill` buf
__global__ __launch_bounds__(256) void k_csr(
    const int* __restrict__ ei, const int* __restrict__ et,
    const int* __restrict__ offs, int* __restrict__ cnt, int* __restrict__ csr) {
  int e = blockIdx.x * 256 + threadIdx.x;
  if (e < NE) {
    int src = ei[e];
    int key = ei[NE + e] * NR + et[e];
    int old = atomicSub(&cnt[key], 1);
    csr[offs[key] + old - 1] = src;
  }
}

// ---- fused per-layer kernel -------------------------------------------------
// Block (256 thr, 4 waves) owns 16 dst nodes = 128 contiguous (dst,rel) CSR
// segments. Branch-free position-parallel edge streaming (16 gathers in flight
// per wave), LDS f32 accumulation via hardware ds_add_f32 (unsafeAtomicAdd;
// plain atomicAdd on LDS floats compiles to a CAS loop = round-3's 4.5x
// regression), then MFMA from LDS.
template <int RELU, int OUTBF>
__global__ __launch_bounds__(256, 2) void k_fused(
    const unsigned short* __restrict__ xb,   // [N][128] bf16
    const unsigned short* __restrict__ wl,   // [9][128][128] n-major bf16
    const int* __restrict__ offs, const int* __restrict__ csr,
    const float* __restrict__ bias, void* __restrict__ outp) {
  __shared__ int sOffs[132];
  __shared__ float sAgg[16 * ROWS + 132];    // [16 nodes][8 rel][128] f32 + dummy row
  __shared__ float sU[MAPC];                 // union: pos->key map (int) / C partials
  int* sUi = (int*)sU;

  const int tid = threadIdx.x;
  const int w = tid >> 6;
  const int lane = tid & 63;
  const int m = lane & 15, q = lane >> 4;
  const int n0 = blockIdx.x * 16;
  const int k0 = n0 * NR;

  // init: offsets + zero agg
  if (tid < 132) sOffs[tid] = offs[(k0 + tid <= NKEY) ? k0 + tid : NKEY];
  for (int i = tid; i < 16 * ROWS + 132; i += 256) sAgg[i] = 0.f;
  __syncthreads();

  const int E0 = sOffs[0], E1 = sOffs[128];

  // position -> key map (each position covered by exactly one key)
  if (tid < 128) {
    int b = sOffs[tid], e = sOffs[tid + 1];
    for (int p = b; p < e; p++) {
      int rp = p - E0;
      if (rp < MAPC) sUi[rp] = tid;
    }
  }
  __syncthreads();

  // edge phase: wave w takes 16-position chunks, stride 64; branch-free.
  for (int base = E0 + w * 16; base < E1; base += 64) {
    unsigned pv = (unsigned)csr[base + (lane & 15)];   // csr padded +64 ints
    int kks[16];
    ushort2 vv[16];
#pragma unroll
    for (int j = 0; j < 16; j++) {
      int p = base + j;
      unsigned src = __shfl(pv, j) & 0x1FFFFu;         // poison-proof clamp
      src = src < NN ? src : 0u;
      int rp = p - E0;
      int kk;
      if (rp < MAPC) kk = sUi[rp];
      else {                                           // ~never: bsearch fallback
        int lo = 0, hi = 128;
        while (hi - lo > 1) {
          int mid = (lo + hi) >> 1;
          if (sOffs[mid] <= p) lo = mid; else hi = mid;
        }
        kk = lo;
      }
      kks[j] = (p < E1) ? kk : 128;                    // tail -> dummy row
      vv[j] = *(const ushort2*)(xb + (size_t)src * DD + 2 * lane);
    }
#pragma unroll
    for (int j = 0; j < 16; j++) {
      float* dp = &sAgg[(kks[j] >> 3) * ROWS + (kks[j] & 7) * DD + 2 * lane];
      unsafeAtomicAdd(dp, bf2f(vv[j].x));
      unsafeAtomicAdd(dp + 1, bf2f(vv[j].y));
    }
  }
  __syncthreads();

  // A-frag build: wave w -> rels {2w, 2w+1}; wave 3 also root (from xb)
  const int r0 = 2 * w, r1 = 2 * w + 1;
  short8 aF[2][4], aR[4];
  {
    float c0 = (float)(sOffs[m * 8 + r0 + 1] - sOffs[m * 8 + r0]);
    float c1 = (float)(sOffs[m * 8 + r1 + 1] - sOffs[m * 8 + r1]);
    float nm0 = 1.0f / fmaxf(c0, 1.0f);
    float nm1 = 1.0f / fmaxf(c1, 1.0f);
#pragma unroll
    for (int ks = 0; ks < 4; ks++) {
      const float* p0 = &sAgg[m * ROWS + r0 * DD + ks * 32 + q * 8];
      const float* p1 = &sAgg[m * ROWS + r1 * DD + ks * 32 + q * 8];
      f32x4 u0 = *(const f32x4*)p0, u0b = *(const f32x4*)(p0 + 4);
      f32x4 u1 = *(const f32x4*)p1, u1b = *(const f32x4*)(p1 + 4);
      short8 t0, t1;
#pragma unroll
      for (int j = 0; j < 4; j++) {
        t0[j] = (short)f2bf(u0[j] * nm0);
        t0[j + 4] = (short)f2bf(u0b[j] * nm0);
        t1[j] = (short)f2bf(u1[j] * nm1);
        t1[j + 4] = (short)f2bf(u1b[j] * nm1);
      }
      aF[0][ks] = t0;
      aF[1][ks] = t1;
    }
    if (w == 3) {
#pragma unroll
      for (int ks = 0; ks < 4; ks++)
        aR[ks] = *(const short8*)(xb + (size_t)(n0 + m) * DD + ks * 32 + q * 8);
    }
  }
  __syncthreads();
  // zero C-partial buffer (reuses map region)
  for (int i = tid; i < MAPC; i += 256) sU[i] = 0.f;
  __syncthreads();

  // MFMA: accumulate this wave's matrices, then LDS f32-atomic C reduce
  f32x4 acc[8];
#pragma unroll
  for (int nt = 0; nt < 8; nt++) acc[nt] = (f32x4){0.f, 0.f, 0.f, 0.f};
  const int nmat = (w == 3) ? 3 : 2;
  for (int rr = 0; rr < nmat; rr++) {
    const int mid = (rr == 2) ? 8 : (rr == 0 ? r0 : r1);
    const unsigned short* wr = wl + mid * DD * DD;
#pragma unroll
    for (int nt = 0; nt < 8; nt++) {
      const unsigned short* wp = wr + (nt * 16 + m) * DD + q * 8;
#pragma unroll
      for (int ks = 0; ks < 4; ks++) {
        short8 b = *(const short8*)(wp + ks * 32);
        short8 a = (rr == 2) ? aR[ks] : aF[rr][ks];
        acc[nt] = __builtin_amdgcn_mfma_f32_16x16x32_bf16(a, b, acc[nt], 0, 0, 0);
      }
    }
  }
  // C/D layout: row = q*4+i, col = nt*16+m
#pragma unroll
  for (int nt = 0; nt < 8; nt++)
#pragma unroll
    for (int i = 0; i < 4; i++)
      unsafeAtomicAdd(&sU[(q * 4 + i) * 132 + nt * 16 + m], acc[nt][i]);
  __syncthreads();

  // epilogue: 256 thr x 8 cols; add bias, relu, write
  {
    int row = tid >> 4;
    int c0 = (tid & 15) * 8;
    float vvv[8];
#pragma unroll
    for (int j = 0; j < 8; j++) {
      vvv[j] = sU[row * 132 + c0 + j] + bias[c0 + j];
      if (RELU) vvv[j] = fmaxf(vvv[j], 0.f);
    }
    if (OUTBF) {
      ushort4 o0, o1;
      o0.x = f2bf(vvv[0]); o0.y = f2bf(vvv[1]); o0.z = f2bf(vvv[2]); o0.w = f2bf(vvv[3]);
      o1.x = f2bf(vvv[4]); o1.y = f2bf(vvv[5]); o1.z = f2bf(vvv[6]); o1.w = f2bf(vvv[7]);
      unsigned short* ob = (unsigned short*)outp + (size_t)(n0 + row) * DD + c0;
      *(ushort4*)ob = o0;
      *(ushort4*)(ob + 4) = o1;
    } else {
      float* ob = (float*)outp + (size_t)(n0 + row) * DD + c0;
      *(float4*)ob = *(float4*)vvv;
      *(float4*)(ob + 4) = *(float4*)(vvv + 4);
    }
  }
}

// ---- launch -----------------------------------------------------------------

extern "C" void kernel_launch(void* const* d_in, const int* in_sizes, int n_in,
                              void* d_out, int out_size, void* d_ws, size_t ws_size,
                              hipStream_t stream) {
  const float* x     = (const float*)d_in[0];
  const int*   ei    = (const int*)d_in[1];
  const int*   et    = (const int*)d_in[2];
  const float* W1    = (const float*)d_in[3];
  const float* root1 = (const float*)d_in[4];
  const float* b1    = (const float*)d_in[5];
  const float* W2    = (const float*)d_in[6];
  const float* root2 = (const float*)d_in[7];
  const float* b2    = (const float*)d_in[8];
  float* out = (float*)d_out;

  char* p = (char*)d_ws;
  unsigned short* xb1 = (unsigned short*)p; p += (size_t)NN * DD * 2;   // 25.6 MB
  unsigned short* xb2 = (unsigned short*)p; p += (size_t)NN * DD * 2;   // 25.6 MB
  unsigned short* wbf = (unsigned short*)p; p += (size_t)2 * 9 * DD * DD * 2;
  int* cnt  = (int*)p; p += (size_t)NKEY * 4;                           // 3.2 MB
  int* offs = (int*)p; p += (size_t)(NKEY + 16) * 4;                    // 3.2 MB
  int* bsum = (int*)p; p += (size_t)1024 * 4;
  int* csr  = (int*)p; p += (size_t)(NE + 64) * 4;                      // 6.4 MB (+pad for branch-free reads)
  // total ~= 64 MB

  k_cast<<<(NN * DD / 4 + 255) / 256, 256, 0, stream>>>(x, xb1);
  k_wtrans<<<(2 * 9 * 16384) / 256, 256, 0, stream>>>(W1, root1, W2, root2, wbf);
  k_zero<<<(NKEY + 255) / 256, 256, 0, stream>>>(cnt, NKEY);
  k_count<<<(NE + 255) / 256, 256, 0, stream>>>(ei, et, cnt);
  k_scan1<<<NBLK, 1024, 0, stream>>>(cnt, offs, bsum);
  k_scan2<<<1, 1024, 0, stream>>>(bsum);
  k_scan3<<<(NKEY + 255) / 256, 256, 0, stream>>>(offs, bsum);
  k_csr<<<(NE + 255) / 256, 256, 0, stream>>>(ei, et, offs, cnt, csr);

  dim3 fgrid(NN / 16);   // 6250, NN divisible by 16
  k_fused<1, 1><<<fgrid, 256, 0, stream>>>(xb1, wbf, offs, csr, b1, (void*)xb2);
  k_fused<0, 0><<<fgrid, 256, 0, stream>>>(xb2, wbf + 9 * DD * DD, offs, csr, b2, (void*)out);
}

// Round 5
// 744.113 us; speedup vs baseline: 6.2044x; 6.2044x over previous
//
#include <hip/hip_runtime.h>

#define NN 100000   // nodes
#define NE 1600000  // edges
#define NR 8        // relations
#define DD 128      // feature dim
#define NKEY (NN * NR)               // 800000 (dst,rel) keys
#define NBLK ((NKEY + 1023) / 1024)  // 782 scan blocks
#define RSTRIDE 580                  // sAgg row stride in dwords (4*odd -> clean banks)

typedef __attribute__((ext_vector_type(8))) short short8;
typedef __attribute__((ext_vector_type(4))) float f32x4;

__device__ __forceinline__ float bf2f(unsigned short u) {
  union { unsigned int i; float f; } c; c.i = ((unsigned int)u) << 16; return c.f;
}
__device__ __forceinline__ unsigned short f2bf(float f) {
  union { float f; unsigned int i; } c; c.f = f;
  unsigned int u = c.i;
  return (unsigned short)((u + 0x7FFFu + ((u >> 16) & 1u)) >> 16);  // RNE
}

// ---- preprocessing ----------------------------------------------------------

__global__ __launch_bounds__(256) void k_cast(
    const float* __restrict__ x, unsigned short* __restrict__ xb) {
  int i = blockIdx.x * 256 + threadIdx.x;          // over N*D/4
  if (i < NN * DD / 4) {
    float4 f = ((const float4*)x)[i];
    ushort4 u;
    u.x = f2bf(f.x); u.y = f2bf(f.y); u.z = f2bf(f.z); u.w = f2bf(f.w);
    ((ushort4*)xb)[i] = u;
  }
}

// wbf[layer][rb][n][k] = W[rb][k][n]  (rb==8 -> root), bf16
__global__ __launch_bounds__(256) void k_wtrans(
    const float* __restrict__ W1, const float* __restrict__ root1,
    const float* __restrict__ W2, const float* __restrict__ root2,
    unsigned short* __restrict__ wbf) {
  int idx = blockIdx.x * 256 + threadIdx.x;        // 2*9*16384 total
  int layer = idx / (9 * 16384);
  int rem = idx % (9 * 16384);
  int r = rem / 16384;
  int nk = rem % 16384;
  int n = nk >> 7, k = nk & 127;
  float v;
  if (r < 8) v = (layer ? W2 : W1)[r * 16384 + k * 128 + n];
  else       v = (layer ? root2 : root1)[k * 128 + n];
  wbf[idx] = f2bf(v);
}

__global__ __launch_bounds__(256) void k_zero(int* __restrict__ p, int n) {
  int i = blockIdx.x * 256 + threadIdx.x;
  if (i < n) p[i] = 0;
}

__global__ __launch_bounds__(256) void k_count(
    const int* __restrict__ ei, const int* __restrict__ et, int* __restrict__ cnt) {
  int e = blockIdx.x * 256 + threadIdx.x;
  if (e < NE) {
    int dst = ei[NE + e];
    int r = et[e];
    atomicAdd(&cnt[dst * NR + r], 1);
  }
}

// hierarchical exclusive scan over NKEY elements
__global__ __launch_bounds__(1024) void k_scan1(
    const int* __restrict__ cnt, int* __restrict__ offs, int* __restrict__ bsum) {
  __shared__ int sd[1024];
  int t = threadIdx.x, b = blockIdx.x;
  int i = b * 1024 + t;
  int v = (i < NKEY) ? cnt[i] : 0;
  sd[t] = v;
  __syncthreads();
  for (int o = 1; o < 1024; o <<= 1) {
    int tv = (t >= o) ? sd[t - o] : 0;
    __syncthreads();
    sd[t] += tv;
    __syncthreads();
  }
  if (i < NKEY) offs[i] = sd[t] - v;               // block-local exclusive
  if (t == 1023) bsum[b] = sd[t];
}

__global__ __launch_bounds__(1024) void k_scan2(int* __restrict__ bsum) {
  __shared__ int sd[1024];
  int t = threadIdx.x;
  int v = (t < NBLK) ? bsum[t] : 0;
  sd[t] = v;
  __syncthreads();
  for (int o = 1; o < 1024; o <<= 1) {
    int tv = (t >= o) ? sd[t - o] : 0;
    __syncthreads();
    sd[t] += tv;
    __syncthreads();
  }
  if (t < NBLK) bsum[t] = sd[t] - v;               // exclusive block bases
}

__global__ __launch_bounds__(256) void k_scan3(
    int* __restrict__ offs, const int* __restrict__ bsum) {
  int i = blockIdx.x * 256 + threadIdx.x;
  if (i < NKEY) offs[i] += bsum[i >> 10];
  if (i == 0) offs[NKEY] = NE;                     // total is always NE
}

// scatter edges; reuses cnt as the fill counter (atomicSub), so no `fill` buf
__global__ __launch_bounds__(256) void k_csr(
    const int* __restrict__ ei, const int* __restrict__ et,
    const int* __restrict__ offs, int* __restrict__ cnt, int* __restrict__ csr) {
  int e = blockIdx.x * 256 + threadIdx.x;
  if (e < NE) {
    int src = ei[e];
    int key = ei[NE + e] * NR + et[e];
    int old = atomicSub(&cnt[key], 1);
    csr[offs[key] + old - 1] = src;
  }
}

// ---- fused per-layer kernel -------------------------------------------------
// Block (256 thr, 4 waves) owns 16 dst nodes = 128 (dst,rel) keys. Wave w owns
// keys 32w..32w+31 (a contiguous csr range): streams edges with an 8-deep
// software-pipelined row gather, accumulates the current key's sum in 2 VGPRs,
// and flushes the normalized bf16 mean ONCE per key with a plain ds_write —
// zero atomics (rounds 3/4 showed LDS float atomicAdd compiles to a CAS loop).
// MFMA phase: wave w computes output cols 32w..32w+31 over all 9 matrices
// (A re-read from LDS per matrix) — no C-reduce partials.
template <int RELU, int OUTBF>
__global__ __launch_bounds__(256, 4) void k_fused(
    const unsigned short* __restrict__ xb,   // [N][128] bf16
    const unsigned short* __restrict__ wl,   // [9][128][128] n-major bf16
    const int* __restrict__ offs, const int* __restrict__ csr,
    const float* __restrict__ bias, void* __restrict__ outp) {
  __shared__ unsigned int sAgg32[16 * RSTRIDE];    // [16 nodes][9*128+8] bf16, 37120 B
  const unsigned short* sAggH = (const unsigned short*)sAgg32;

  const int tid = threadIdx.x;
  const int w = tid >> 6;
  const int lane = tid & 63;
  const int m = lane & 15, q = lane >> 4;
  const int n0 = blockIdx.x * 16;
  const int k0 = n0 * NR;

  // this wave's 33 key offsets, one per lane (lane 0..32)
  int oidx = k0 + 32 * w + lane;
  if (oidx > NKEY) oidx = NKEY;
  const int offv = offs[oidx];
  const int p0 = __shfl(offv, 0);
  const int p1 = __shfl(offv, 32);

  // root row for this wave's 4 nodes: xb -> sAgg slot 8 (bf16 passthrough)
#pragma unroll
  for (int i = 0; i < 4; i++) {
    int node = 4 * w + i;
    unsigned int v = *(const unsigned int*)(xb + (size_t)(n0 + node) * DD + 2 * lane);
    sAgg32[node * RSTRIDE + 8 * 64 + lane] = v;
  }

  // ---- edge phase ----
  int kloc = 0;
  int kbeg = p0;
  int kend = __shfl(offv, 1);
  float ax = 0.f, ay = 0.f;

  int wbase = p0;                                  // csr window [wbase, wbase+64)
  int pv = csr[wbase + lane];                      // csr padded +64 ints
  ushort2 vb[8];
#pragma unroll
  for (int j = 0; j < 8; j++) {
    unsigned s = (unsigned)__shfl(pv, j);
    s = s < NN ? s : 0u;                           // pad/poison-proof
    vb[j] = *(const ushort2*)(xb + (size_t)s * DD + 2 * lane);
  }

  for (int base = p0; base < p1; base += 8) {
    const int nbase = base + 8;
    if (((nbase - p0) & 63) == 0) {                // slide csr window
      wbase = nbase;
      pv = csr[wbase + lane];
    }
    ushort2 nv[8];
#pragma unroll
    for (int j = 0; j < 8; j++) {                  // issue next 8 gathers
      unsigned s = (unsigned)__shfl(pv, nbase - wbase + j);
      s = s < NN ? s : 0u;
      nv[j] = *(const ushort2*)(xb + (size_t)s * DD + 2 * lane);
    }
#pragma unroll
    for (int j = 0; j < 8; j++) {                  // consume current 8
      if (base + j < p1) {
        while (base + j >= kend) {                 // key transition(s): flush
          float nm = __builtin_amdgcn_rcpf(fmaxf((float)(kend - kbeg), 1.f));
          unsigned lo = f2bf(ax * nm), hi = f2bf(ay * nm);
          int node = 4 * w + (kloc >> 3);
          sAgg32[node * RSTRIDE + (kloc & 7) * 64 + lane] = lo | (hi << 16);
          ax = 0.f; ay = 0.f;
          kloc++;
          kbeg = kend;
          kend = __shfl(offv, kloc + 1);
        }
        ax += bf2f(vb[j].x);
        ay += bf2f(vb[j].y);
      }
    }
#pragma unroll
    for (int j = 0; j < 8; j++) vb[j] = nv[j];
  }
  // drain remaining keys (incl. empty)
  while (kloc < 32) {
    float nm = __builtin_amdgcn_rcpf(fmaxf((float)(kend - kbeg), 1.f));
    unsigned lo = f2bf(ax * nm), hi = f2bf(ay * nm);
    int node = 4 * w + (kloc >> 3);
    sAgg32[node * RSTRIDE + (kloc & 7) * 64 + lane] = lo | (hi << 16);
    ax = 0.f; ay = 0.f;
    kloc++;
    kbeg = kend;
    kend = (kloc < 32) ? __shfl(offv, kloc + 1) : kend;
  }
  __syncthreads();

  // ---- MFMA phase: wave w -> output cols 32w..32w+31, all 9 matrices ----
  f32x4 acc0 = {0.f, 0.f, 0.f, 0.f}, acc1 = {0.f, 0.f, 0.f, 0.f};
  const int nt0 = 2 * w, nt1 = 2 * w + 1;
  for (int mat = 0; mat < 9; mat++) {
    short8 a[4];
#pragma unroll
    for (int ks = 0; ks < 4; ks++)
      a[ks] = *(const short8*)(sAggH + m * (2 * RSTRIDE) + mat * 128 + ks * 32 + q * 8);
    const unsigned short* wr = wl + mat * DD * DD;
#pragma unroll
    for (int ks = 0; ks < 4; ks++) {
      short8 b0 = *(const short8*)(wr + (nt0 * 16 + m) * DD + ks * 32 + q * 8);
      short8 b1 = *(const short8*)(wr + (nt1 * 16 + m) * DD + ks * 32 + q * 8);
      acc0 = __builtin_amdgcn_mfma_f32_16x16x32_bf16(a[ks], b0, acc0, 0, 0, 0);
      acc1 = __builtin_amdgcn_mfma_f32_16x16x32_bf16(a[ks], b1, acc1, 0, 0, 0);
    }
  }

  // epilogue: C/D row = q*4+i, col = nt*16+m
  {
    const int c0 = nt0 * 16 + m, c1 = nt1 * 16 + m;
    const float bv0 = bias[c0], bv1 = bias[c1];
#pragma unroll
    for (int i = 0; i < 4; i++) {
      int row = n0 + q * 4 + i;
      float v0 = acc0[i] + bv0, v1 = acc1[i] + bv1;
      if (RELU) { v0 = fmaxf(v0, 0.f); v1 = fmaxf(v1, 0.f); }
      if (OUTBF) {
        unsigned short* ob = (unsigned short*)outp + (size_t)row * DD;
        ob[c0] = f2bf(v0);
        ob[c1] = f2bf(v1);
      } else {
        float* ob = (float*)outp + (size_t)row * DD;
        ob[c0] = v0;
        ob[c1] = v1;
      }
    }
  }
}

// ---- launch -----------------------------------------------------------------

extern "C" void kernel_launch(void* const* d_in, const int* in_sizes, int n_in,
                              void* d_out, int out_size, void* d_ws, size_t ws_size,
                              hipStream_t stream) {
  const float* x     = (const float*)d_in[0];
  const int*   ei    = (const int*)d_in[1];
  const int*   et    = (const int*)d_in[2];
  const float* W1    = (const float*)d_in[3];
  const float* root1 = (const float*)d_in[4];
  const float* b1    = (const float*)d_in[5];
  const float* W2    = (const float*)d_in[6];
  const float* root2 = (const float*)d_in[7];
  const float* b2    = (const float*)d_in[8];
  float* out = (float*)d_out;

  char* p = (char*)d_ws;
  unsigned short* xb1 = (unsigned short*)p; p += (size_t)NN * DD * 2;   // 25.6 MB
  unsigned short* xb2 = (unsigned short*)p; p += (size_t)NN * DD * 2;   // 25.6 MB
  unsigned short* wbf = (unsigned short*)p; p += (size_t)2 * 9 * DD * DD * 2;
  int* cnt  = (int*)p; p += (size_t)NKEY * 4;                           // 3.2 MB
  int* offs = (int*)p; p += (size_t)(NKEY + 16) * 4;                    // 3.2 MB
  int* bsum = (int*)p; p += (size_t)1024 * 4;
  int* csr  = (int*)p; p += (size_t)(NE + 64) * 4;                      // 6.4 MB (+pad)
  // total ~= 64 MB

  k_cast<<<(NN * DD / 4 + 255) / 256, 256, 0, stream>>>(x, xb1);
  k_wtrans<<<(2 * 9 * 16384) / 256, 256, 0, stream>>>(W1, root1, W2, root2, wbf);
  k_zero<<<(NKEY + 255) / 256, 256, 0, stream>>>(cnt, NKEY);
  k_count<<<(NE + 255) / 256, 256, 0, stream>>>(ei, et, cnt);
  k_scan1<<<NBLK, 1024, 0, stream>>>(cnt, offs, bsum);
  k_scan2<<<1, 1024, 0, stream>>>(bsum);
  k_scan3<<<(NKEY + 255) / 256, 256, 0, stream>>>(offs, bsum);
  k_csr<<<(NE + 255) / 256, 256, 0, stream>>>(ei, et, offs, cnt, csr);

  dim3 fgrid(NN / 16);   // 6250
  k_fused<1, 1><<<fgrid, 256, 0, stream>>>(xb1, wbf, offs, csr, b1, (void*)xb2);
  k_fused<0, 0><<<fgrid, 256, 0, stream>>>(xb2, wbf + 9 * DD * DD, offs, csr, b2, (void*)out);
}